// Round 3
// baseline (1758.997 us; speedup 1.0000x reference)
//
#include <hip/hip_runtime.h>
#include <hip/hip_fp16.h>

#define N_NODES 50000
#define N_EDGES 800000
#define NGRAPH  256
#define FDIM    64
#define EDIM    16

// ---------------- small setup kernels ----------------

__global__ void k_init_out(float* __restrict__ out, const float* __restrict__ b_out) {
    int g = blockIdx.x * blockDim.x + threadIdx.x;
    if (g < NGRAPH) out[g] = b_out[0];
}

__global__ void k_count(const int* __restrict__ dst, int* __restrict__ cnt) {
    int e = blockIdx.x * blockDim.x + threadIdx.x;
    if (e < N_EDGES) atomicAdd(&cnt[dst[e]], 1);
}

__global__ void k_ea_scatter(const int* __restrict__ dst,
                             const float* __restrict__ edge_attr,
                             float* __restrict__ ea) {
    int t = blockIdx.x * blockDim.x + threadIdx.x;
    if (t < N_EDGES * EDIM) {
        int e = t >> 4;
        int c = t & 15;
        atomicAdd(&ea[dst[e] * EDIM + c], edge_attr[t]);
    }
}

__global__ void k_cvt_x(const float* __restrict__ x, __half* __restrict__ x16) {
    int t = blockIdx.x * blockDim.x + threadIdx.x;
    if (t < N_NODES * FDIM) x16[t] = __float2half(x[t]);
}

// single-block exclusive scan of cnt -> rowp (N+1), also init cursor
__global__ void k_scan(const int* __restrict__ cnt, int* __restrict__ rowp,
                       int* __restrict__ cur) {
    __shared__ int part[1024];
    int t = threadIdx.x;
    const int CH = (N_NODES + 1023) / 1024;
    int s = 0;
    int start = t * CH;
    for (int i = 0; i < CH; i++) {
        int idx = start + i;
        if (idx < N_NODES) s += cnt[idx];
    }
    part[t] = s;
    __syncthreads();
    for (int off = 1; off < 1024; off <<= 1) {
        int v = (t >= off) ? part[t - off] : 0;
        __syncthreads();
        part[t] += v;
        __syncthreads();
    }
    int run = (t == 0) ? 0 : part[t - 1];
    for (int i = 0; i < CH; i++) {
        int idx = start + i;
        if (idx < N_NODES) {
            rowp[idx] = run;
            cur[idx]  = run;
            run += cnt[idx];
        }
    }
    if (t == 1023) rowp[N_NODES] = part[1023];
}

__global__ void k_fill(const int* __restrict__ src, const int* __restrict__ dst,
                       int* __restrict__ cur, int* __restrict__ col) {
    int e = blockIdx.x * blockDim.x + threadIdx.x;
    if (e < N_EDGES) {
        int pos = atomicAdd(&cur[dst[e]], 1);
        col[pos] = src[e];
    }
}

// ---------------- gather helper ----------------
// Sum rows of h16 (64 x fp16, 128B) listed in col[beg:end).
// Whole wave: 2 edges per load instruction; indices are wave-uniform scalar
// loads; up to 16 edges (8 loads) in flight. Returns per-lane partial for
// feature pair (2c, 2c+1) where c = lane & 31; caller combines halves via
// shfl_xor(32).
__device__ __forceinline__ void gather_rows(const __half2* __restrict__ h2,
                                            const int* __restrict__ col,
                                            int beg, int end, int lane, int c,
                                            float& a0, float& a1) {
    int p = beg;
    while (p + 16 <= end) {
        int js[16];
#pragma unroll
        for (int k = 0; k < 16; k++) js[k] = col[p + k];
#pragma unroll
        for (int k = 0; k < 8; k++) {
            int jj = (lane < 32) ? js[2 * k] : js[2 * k + 1];
            float2 f = __half22float2(h2[jj * 32 + c]);
            a0 += f.x; a1 += f.y;
        }
        p += 16;
    }
    if (p + 8 <= end) {
        int js[8];
#pragma unroll
        for (int k = 0; k < 8; k++) js[k] = col[p + k];
#pragma unroll
        for (int k = 0; k < 4; k++) {
            int jj = (lane < 32) ? js[2 * k] : js[2 * k + 1];
            float2 f = __half22float2(h2[jj * 32 + c]);
            a0 += f.x; a1 += f.y;
        }
        p += 8;
    }
    while (p + 2 <= end) {
        int jA = col[p], jB = col[p + 1];
        int jj = (lane < 32) ? jA : jB;
        float2 f = __half22float2(h2[jj * 32 + c]);
        a0 += f.x; a1 += f.y;
        p += 2;
    }
    if (p < end && lane < 32) {
        float2 f = __half22float2(h2[col[p] * 32 + c]);
        a0 += f.x; a1 += f.y;
    }
}

// ---------------- fused per-node kernels (wave per node, no barriers) ----
// h0 = relu(x @ Wnh + bnh);  base = h0 + bmh + (ea_agg + 1s) @ Wmh[128:144]
__global__ void k_h0base(const float* __restrict__ x, const float* __restrict__ ea,
                         const float* __restrict__ Wnh, const float* __restrict__ bnh,
                         const float* __restrict__ Wmh, const float* __restrict__ bmh,
                         float* __restrict__ h0out, __half* __restrict__ h0out16,
                         float* __restrict__ baseout) {
    __shared__ __align__(16) float sx[4][FDIM];
    __shared__ __align__(16) float sea[4][EDIM];
    int lane = threadIdx.x & 63;
    int wid  = threadIdx.x >> 6;
    float wnh[FDIM], w3[EDIM];
#pragma unroll
    for (int m = 0; m < FDIM; m++) wnh[m] = Wnh[m * FDIM + lane];
    float csum = 0.f;
#pragma unroll
    for (int m = 0; m < EDIM; m++) {
        w3[m] = Wmh[(2 * FDIM + m) * FDIM + lane];
        csum += w3[m];
    }
    float bnhk = bnh[lane], bmhk = bmh[lane];
    int gw = blockIdx.x * 4 + wid;
    int nw = gridDim.x * 4;
    for (int i = gw; i < N_NODES; i += nw) {
        sx[wid][lane] = x[i * FDIM + lane];
        if (lane < EDIM) sea[wid][lane] = ea[i * EDIM + lane];
        float acc = bnhk;
        const float4* s4 = (const float4*)sx[wid];
#pragma unroll
        for (int m4 = 0; m4 < FDIM / 4; m4++) {
            float4 v = s4[m4];
            acc = fmaf(v.x, wnh[4 * m4 + 0], acc);
            acc = fmaf(v.y, wnh[4 * m4 + 1], acc);
            acc = fmaf(v.z, wnh[4 * m4 + 2], acc);
            acc = fmaf(v.w, wnh[4 * m4 + 3], acc);
        }
        float h0 = fmaxf(acc, 0.f);
        float b = h0 + bmhk + csum;
        const float4* e4 = (const float4*)sea[wid];
#pragma unroll
        for (int m4 = 0; m4 < EDIM / 4; m4++) {
            float4 v = e4[m4];
            b = fmaf(v.x, w3[4 * m4 + 0], b);
            b = fmaf(v.y, w3[4 * m4 + 1], b);
            b = fmaf(v.z, w3[4 * m4 + 2], b);
            b = fmaf(v.w, w3[4 * m4 + 3], b);
        }
        h0out[i * FDIM + lane]   = h0;
        h0out16[i * FDIM + lane] = __float2half(h0);
        baseout[i * FDIM + lane] = b;
    }
}

// obase = (x[i] + sum_in x[j]) @ Wom[128:192] + bom   (no relu)
__global__ void k_obase(const float* __restrict__ x, const __half* __restrict__ x16,
                        const int* __restrict__ rowp, const int* __restrict__ col,
                        const float* __restrict__ Wom, const float* __restrict__ bom,
                        float* __restrict__ obase) {
    __shared__ __align__(16) float2 sf2[4][FDIM / 2];
    int lane = threadIdx.x & 63, wid = threadIdx.x >> 6;
    int c = lane & 31;
    float w3[FDIM];
#pragma unroll
    for (int m = 0; m < FDIM; m++) w3[m] = Wom[(2 * FDIM + m) * FDIM + lane];
    float bk = bom[lane];
    const __half2* h2 = (const __half2*)x16;
    int gw = blockIdx.x * 4 + wid, nw = gridDim.x * 4;
    for (int i = gw; i < N_NODES; i += nw) {
        int beg = rowp[i], end = rowp[i + 1];
        float a0 = 0.f, a1 = 0.f;
        gather_rows(h2, col, beg, end, lane, c, a0, a1);
        a0 += __shfl_xor(a0, 32, 64);
        a1 += __shfl_xor(a1, 32, 64);
        if (lane < 32) {
            float2 xv = ((const float2*)(x + i * FDIM))[c];
            sf2[wid][c] = make_float2(a0 + xv.x, a1 + xv.y);
        }
        float acc = bk;
        const float4* s4 = (const float4*)sf2[wid];
#pragma unroll
        for (int m4 = 0; m4 < FDIM / 4; m4++) {
            float4 v = s4[m4];
            acc = fmaf(v.x, w3[4 * m4 + 0], acc);
            acc = fmaf(v.y, w3[4 * m4 + 1], acc);
            acc = fmaf(v.z, w3[4 * m4 + 2], acc);
            acc = fmaf(v.w, w3[4 * m4 + 3], acc);
        }
        obase[i * FDIM + lane] = acc;
    }
}

// h_out = relu( (deg*h) @ W1 + (A h) @ W2 + base ), fp16 gather
__global__ void k_layer(const float* __restrict__ hin32, const __half* __restrict__ hin16,
                        const float* __restrict__ base,
                        const int* __restrict__ rowp, const int* __restrict__ col,
                        const float* __restrict__ Wmh,
                        float* __restrict__ hout32, __half* __restrict__ hout16) {
    __shared__ __align__(16) float4 sm4[4][FDIM / 2];
    int lane = threadIdx.x & 63, wid = threadIdx.x >> 6;
    int c = lane & 31;
    float w1[FDIM], w2[FDIM];
#pragma unroll
    for (int m = 0; m < FDIM; m++) {
        w1[m] = Wmh[m * FDIM + lane];
        w2[m] = Wmh[(FDIM + m) * FDIM + lane];
    }
    const __half2* h2 = (const __half2*)hin16;
    int gw = blockIdx.x * 4 + wid, nw = gridDim.x * 4;
    for (int i = gw; i < N_NODES; i += nw) {
        int beg = rowp[i], end = rowp[i + 1];
        float a0 = 0.f, a1 = 0.f;
        gather_rows(h2, col, beg, end, lane, c, a0, a1);
        a0 += __shfl_xor(a0, 32, 64);
        a1 += __shfl_xor(a1, 32, 64);
        if (lane < 32) {
            float2 hv = ((const float2*)(hin32 + i * FDIM))[c];
            float degf = (float)(end - beg + 1);
            sm4[wid][c] = make_float4(degf * hv.x, a0 + hv.x,
                                      degf * hv.y, a1 + hv.y);
        }
        float acc = base[i * FDIM + lane];
        const float4* s4 = (const float4*)sm4[wid];
#pragma unroll
        for (int m2 = 0; m2 < 32; m2++) {
            float4 v = s4[m2];
            acc = fmaf(v.x, w1[2 * m2], acc);
            acc = fmaf(v.y, w2[2 * m2], acc);
            acc = fmaf(v.z, w1[2 * m2 + 1], acc);
            acc = fmaf(v.w, w2[2 * m2 + 1], acc);
        }
        float h = fmaxf(acc, 0.f);
        hout32[i * FDIM + lane] = h;
        hout16[i * FDIM + lane] = __float2half(h);
    }
}

// out = relu( (deg*h)@Wom1 + (A h)@Wom2 + obase ); scalar = out.Wout; atomic pool
__global__ void k_out(const float* __restrict__ hin32, const __half* __restrict__ hin16,
                      const float* __restrict__ obase,
                      const int* __restrict__ rowp, const int* __restrict__ col,
                      const float* __restrict__ Wom,
                      const float* __restrict__ Wout,
                      const int* __restrict__ batch,
                      float* __restrict__ dout) {
    __shared__ __align__(16) float4 sm4[4][FDIM / 2];
    int lane = threadIdx.x & 63, wid = threadIdx.x >> 6;
    int c = lane & 31;
    float w1[FDIM], w2[FDIM];
#pragma unroll
    for (int m = 0; m < FDIM; m++) {
        w1[m] = Wom[m * FDIM + lane];
        w2[m] = Wom[(FDIM + m) * FDIM + lane];
    }
    float wo = Wout[lane];
    const __half2* h2 = (const __half2*)hin16;
    int gw = blockIdx.x * 4 + wid, nw = gridDim.x * 4;
    for (int i = gw; i < N_NODES; i += nw) {
        int beg = rowp[i], end = rowp[i + 1];
        float a0 = 0.f, a1 = 0.f;
        gather_rows(h2, col, beg, end, lane, c, a0, a1);
        a0 += __shfl_xor(a0, 32, 64);
        a1 += __shfl_xor(a1, 32, 64);
        if (lane < 32) {
            float2 hv = ((const float2*)(hin32 + i * FDIM))[c];
            float degf = (float)(end - beg + 1);
            sm4[wid][c] = make_float4(degf * hv.x, a0 + hv.x,
                                      degf * hv.y, a1 + hv.y);
        }
        float acc = obase[i * FDIM + lane];
        const float4* s4 = (const float4*)sm4[wid];
#pragma unroll
        for (int m2 = 0; m2 < 32; m2++) {
            float4 v = s4[m2];
            acc = fmaf(v.x, w1[2 * m2], acc);
            acc = fmaf(v.y, w2[2 * m2], acc);
            acc = fmaf(v.z, w1[2 * m2 + 1], acc);
            acc = fmaf(v.w, w2[2 * m2 + 1], acc);
        }
        float outk = fmaxf(acc, 0.f);
        float cc = outk * wo;
#pragma unroll
        for (int off = 32; off > 0; off >>= 1) cc += __shfl_down(cc, off, 64);
        if (lane == 0) atomicAdd(&dout[batch[i]], cc);
    }
}

// ---------------- launcher ----------------

extern "C" void kernel_launch(void* const* d_in, const int* in_sizes, int n_in,
                              void* d_out, int out_size, void* d_ws, size_t ws_size,
                              hipStream_t stream) {
    const float* x         = (const float*)d_in[0];
    const float* edge_attr = (const float*)d_in[1];
    const float* Wnh       = (const float*)d_in[2];
    const float* bnh       = (const float*)d_in[3];
    const float* Wmh       = (const float*)d_in[4];
    const float* bmh       = (const float*)d_in[5];
    const float* Wom       = (const float*)d_in[6];
    const float* bom       = (const float*)d_in[7];
    const float* Wout      = (const float*)d_in[8];
    const float* bout      = (const float*)d_in[9];
    const int*   eidx      = (const int*)d_in[10];
    const int*   batch     = (const int*)d_in[11];
    const int*   srcI = eidx;             // edge_index[0] : source (x_j)
    const int*   dstI = eidx + N_EDGES;   // edge_index[1] : target (aggregation)
    float* out = (float*)d_out;
    (void)in_sizes; (void)n_in; (void)out_size;

    char* w = (char*)d_ws;
    size_t off = 0;
    auto take = [&](size_t b) -> void* {
        void* p = w + off;
        off = (off + b + 255) & ~(size_t)255;
        return p;
    };
    float*  ea    = (float*)take((size_t)N_NODES * EDIM * 4);
    int*    cnt   = (int*)take((size_t)N_NODES * 4);
    int*    rowp  = (int*)take((size_t)(N_NODES + 1) * 4);
    int*    cur   = (int*)take((size_t)N_NODES * 4);
    int*    col   = (int*)take((size_t)N_EDGES * 4);
    float*  base  = (float*)take((size_t)N_NODES * FDIM * 4);
    float*  obase = (float*)take((size_t)N_NODES * FDIM * 4);
    float*  hA    = (float*)take((size_t)N_NODES * FDIM * 4);
    float*  hB    = (float*)take((size_t)N_NODES * FDIM * 4);
    __half* x16   = (__half*)take((size_t)N_NODES * FDIM * 2);
    __half* hA16  = (__half*)take((size_t)N_NODES * FDIM * 2);
    __half* hB16  = (__half*)take((size_t)N_NODES * FDIM * 2);
    (void)ws_size;

    hipMemsetAsync(cnt, 0, (size_t)N_NODES * 4, stream);
    hipMemsetAsync(ea, 0, (size_t)N_NODES * EDIM * 4, stream);
    k_init_out<<<1, 256, 0, stream>>>(out, bout);
    k_count<<<(N_EDGES + 255) / 256, 256, 0, stream>>>(dstI, cnt);
    k_ea_scatter<<<(N_EDGES * EDIM + 255) / 256, 256, 0, stream>>>(dstI, edge_attr, ea);
    k_cvt_x<<<(N_NODES * FDIM + 255) / 256, 256, 0, stream>>>(x, x16);
    k_scan<<<1, 1024, 0, stream>>>(cnt, rowp, cur);
    k_fill<<<(N_EDGES + 255) / 256, 256, 0, stream>>>(srcI, dstI, cur, col);
    k_h0base<<<2048, 256, 0, stream>>>(x, ea, Wnh, bnh, Wmh, bmh, hA, hA16, base);
    k_obase<<<2048, 256, 0, stream>>>(x, x16, rowp, col, Wom, bom, obase);
    k_layer<<<2048, 256, 0, stream>>>(hA, hA16, base, rowp, col, Wmh, hB, hB16);
    k_layer<<<2048, 256, 0, stream>>>(hB, hB16, base, rowp, col, Wmh, hA, hA16);
    k_layer<<<2048, 256, 0, stream>>>(hA, hA16, base, rowp, col, Wmh, hB, hB16);
    k_out<<<2048, 256, 0, stream>>>(hB, hB16, obase, rowp, col, Wom, Wout, batch, out);
}

// Round 4
// 994.793 us; speedup vs baseline: 1.7682x; 1.7682x over previous
//
#include <hip/hip_runtime.h>
#include <hip/hip_fp16.h>

#define N_NODES 50000
#define N_EDGES 800000
#define NGRAPH  256
#define FDIM    64
#define EDIM    16

// ---------------- small setup kernels ----------------

__global__ void k_init_out(float* __restrict__ out, const float* __restrict__ b_out) {
    int g = blockIdx.x * blockDim.x + threadIdx.x;
    if (g < NGRAPH) out[g] = b_out[0];
}

__global__ void k_count(const int* __restrict__ dst, int* __restrict__ cnt) {
    int e = blockIdx.x * blockDim.x + threadIdx.x;
    if (e < N_EDGES) atomicAdd(&cnt[dst[e]], 1);
}

__global__ void k_ea_scatter(const int* __restrict__ dst,
                             const float* __restrict__ edge_attr,
                             float* __restrict__ ea) {
    int t = blockIdx.x * blockDim.x + threadIdx.x;
    if (t < N_EDGES * EDIM) {
        int e = t >> 4;
        int c = t & 15;
        atomicAdd(&ea[dst[e] * EDIM + c], edge_attr[t]);
    }
}

__global__ void k_cvt_x(const float* __restrict__ x, __half* __restrict__ x16) {
    int t = blockIdx.x * blockDim.x + threadIdx.x;
    if (t < N_NODES * FDIM) x16[t] = __float2half(x[t]);
}

// single-block exclusive scan of cnt -> rowp (N+1), also init cursor
__global__ void k_scan(const int* __restrict__ cnt, int* __restrict__ rowp,
                       int* __restrict__ cur) {
    __shared__ int part[1024];
    int t = threadIdx.x;
    const int CH = (N_NODES + 1023) / 1024;
    int s = 0;
    int start = t * CH;
    for (int i = 0; i < CH; i++) {
        int idx = start + i;
        if (idx < N_NODES) s += cnt[idx];
    }
    part[t] = s;
    __syncthreads();
    for (int off = 1; off < 1024; off <<= 1) {
        int v = (t >= off) ? part[t - off] : 0;
        __syncthreads();
        part[t] += v;
        __syncthreads();
    }
    int run = (t == 0) ? 0 : part[t - 1];
    for (int i = 0; i < CH; i++) {
        int idx = start + i;
        if (idx < N_NODES) {
            rowp[idx] = run;
            cur[idx]  = run;
            run += cnt[idx];
        }
    }
    if (t == 1023) rowp[N_NODES] = part[1023];
}

__global__ void k_fill(const int* __restrict__ src, const int* __restrict__ dst,
                       int* __restrict__ cur, int* __restrict__ col) {
    int e = blockIdx.x * blockDim.x + threadIdx.x;
    if (e < N_EDGES) {
        int pos = atomicAdd(&cur[dst[e]], 1);
        col[pos] = src[e];
    }
}

// ---------------- gather helper ----------------
// Sum rows of h16 (64 x fp16 = 128B) listed in col[beg:end).
// beg/end MUST be wave-uniform (callers pass readfirstlane'd values) so all
// col[] index loads are scalar (s_load, lgkmcnt) and stay off the vmem path.
// 2 edges per load instruction (half-wave each via cndmask of two scalars);
// 16 edges = 8 __half2 loads in flight per iteration. NO ARRAYS — named
// scalars only, to avoid promote-alloca-to-LDS (R3 regression).
#define LOAD2(JA, JB)                                            \
    {                                                            \
        int jj = (lane < 32) ? (JA) : (JB);                      \
        float2 f = __half22float2(h2[jj * 32 + c]);              \
        a0 += f.x; a1 += f.y;                                    \
    }

__device__ __forceinline__ void gather_rows(const __half2* __restrict__ h2,
                                            const int* __restrict__ col,
                                            int beg, int end, int lane, int c,
                                            float& a0, float& a1) {
    int p = beg;
    for (; p + 16 <= end; p += 16) {
        int j0  = col[p + 0],  j1  = col[p + 1],  j2  = col[p + 2],  j3  = col[p + 3];
        int j4  = col[p + 4],  j5  = col[p + 5],  j6  = col[p + 6],  j7  = col[p + 7];
        int j8  = col[p + 8],  j9  = col[p + 9],  j10 = col[p + 10], j11 = col[p + 11];
        int j12 = col[p + 12], j13 = col[p + 13], j14 = col[p + 14], j15 = col[p + 15];
        LOAD2(j0, j1)   LOAD2(j2, j3)   LOAD2(j4, j5)   LOAD2(j6, j7)
        LOAD2(j8, j9)   LOAD2(j10, j11) LOAD2(j12, j13) LOAD2(j14, j15)
    }
    for (; p + 2 <= end; p += 2) {
        int jA = col[p], jB = col[p + 1];
        LOAD2(jA, jB)
    }
    if (p < end && lane < 32) {
        float2 f = __half22float2(h2[col[p] * 32 + c]);
        a0 += f.x; a1 += f.y;
    }
}

// ---------------- fused per-node kernels (wave per node, no barriers) ----
// h0 = relu(x @ Wnh + bnh);  base = h0 + bmh + (ea_agg + 1s) @ Wmh[128:144]
__global__ void k_h0base(const float* __restrict__ x, const float* __restrict__ ea,
                         const float* __restrict__ Wnh, const float* __restrict__ bnh,
                         const float* __restrict__ Wmh, const float* __restrict__ bmh,
                         float* __restrict__ h0out, __half* __restrict__ h0out16,
                         float* __restrict__ baseout) {
    __shared__ __align__(16) float sx[4][FDIM];
    __shared__ __align__(16) float sea[4][EDIM];
    int lane = threadIdx.x & 63;
    int wid  = threadIdx.x >> 6;
    float wnh[FDIM], w3[EDIM];
#pragma unroll
    for (int m = 0; m < FDIM; m++) wnh[m] = Wnh[m * FDIM + lane];
    float csum = 0.f;
#pragma unroll
    for (int m = 0; m < EDIM; m++) {
        w3[m] = Wmh[(2 * FDIM + m) * FDIM + lane];
        csum += w3[m];
    }
    float bnhk = bnh[lane], bmhk = bmh[lane];
    int gw = blockIdx.x * 4 + wid;
    int nw = gridDim.x * 4;
    for (int i = gw; i < N_NODES; i += nw) {
        sx[wid][lane] = x[i * FDIM + lane];
        if (lane < EDIM) sea[wid][lane] = ea[i * EDIM + lane];
        float acc = bnhk;
        const float4* s4 = (const float4*)sx[wid];
#pragma unroll
        for (int m4 = 0; m4 < FDIM / 4; m4++) {
            float4 v = s4[m4];
            acc = fmaf(v.x, wnh[4 * m4 + 0], acc);
            acc = fmaf(v.y, wnh[4 * m4 + 1], acc);
            acc = fmaf(v.z, wnh[4 * m4 + 2], acc);
            acc = fmaf(v.w, wnh[4 * m4 + 3], acc);
        }
        float h0 = fmaxf(acc, 0.f);
        float b = h0 + bmhk + csum;
        const float4* e4 = (const float4*)sea[wid];
#pragma unroll
        for (int m4 = 0; m4 < EDIM / 4; m4++) {
            float4 v = e4[m4];
            b = fmaf(v.x, w3[4 * m4 + 0], b);
            b = fmaf(v.y, w3[4 * m4 + 1], b);
            b = fmaf(v.z, w3[4 * m4 + 2], b);
            b = fmaf(v.w, w3[4 * m4 + 3], b);
        }
        h0out[i * FDIM + lane]   = h0;
        h0out16[i * FDIM + lane] = __float2half(h0);
        baseout[i * FDIM + lane] = b;
    }
}

// obase = (x[i] + sum_in x[j]) @ Wom[128:192] + bom   (no relu)
__global__ void k_obase(const float* __restrict__ x, const __half* __restrict__ x16,
                        const int* __restrict__ rowp, const int* __restrict__ col,
                        const float* __restrict__ Wom, const float* __restrict__ bom,
                        float* __restrict__ obase) {
    __shared__ __align__(16) float2 sf2[4][FDIM / 2];
    int lane = threadIdx.x & 63, wid = threadIdx.x >> 6;
    int c = lane & 31;
    float w3[FDIM];
#pragma unroll
    for (int m = 0; m < FDIM; m++) w3[m] = Wom[(2 * FDIM + m) * FDIM + lane];
    float bk = bom[lane];
    const __half2* h2 = (const __half2*)x16;
    int gw = blockIdx.x * 4 + wid, nw = gridDim.x * 4;
    for (int i = gw; i < N_NODES; i += nw) {
        int beg = __builtin_amdgcn_readfirstlane(rowp[i]);
        int end = __builtin_amdgcn_readfirstlane(rowp[i + 1]);
        float a0 = 0.f, a1 = 0.f;
        gather_rows(h2, col, beg, end, lane, c, a0, a1);
        a0 += __shfl_xor(a0, 32, 64);
        a1 += __shfl_xor(a1, 32, 64);
        if (lane < 32) {
            float2 xv = ((const float2*)(x + i * FDIM))[c];
            sf2[wid][c] = make_float2(a0 + xv.x, a1 + xv.y);
        }
        float acc = bk;
        const float4* s4 = (const float4*)sf2[wid];
#pragma unroll
        for (int m4 = 0; m4 < FDIM / 4; m4++) {
            float4 v = s4[m4];
            acc = fmaf(v.x, w3[4 * m4 + 0], acc);
            acc = fmaf(v.y, w3[4 * m4 + 1], acc);
            acc = fmaf(v.z, w3[4 * m4 + 2], acc);
            acc = fmaf(v.w, w3[4 * m4 + 3], acc);
        }
        obase[i * FDIM + lane] = acc;
    }
}

// h_out = relu( (deg*h) @ W1 + (A h) @ W2 + base ), fp16 gather
__global__ void k_layer(const float* __restrict__ hin32, const __half* __restrict__ hin16,
                        const float* __restrict__ base,
                        const int* __restrict__ rowp, const int* __restrict__ col,
                        const float* __restrict__ Wmh,
                        float* __restrict__ hout32, __half* __restrict__ hout16) {
    __shared__ __align__(16) float4 sm4[4][FDIM / 2];
    int lane = threadIdx.x & 63, wid = threadIdx.x >> 6;
    int c = lane & 31;
    float w1[FDIM], w2[FDIM];
#pragma unroll
    for (int m = 0; m < FDIM; m++) {
        w1[m] = Wmh[m * FDIM + lane];
        w2[m] = Wmh[(FDIM + m) * FDIM + lane];
    }
    const __half2* h2 = (const __half2*)hin16;
    int gw = blockIdx.x * 4 + wid, nw = gridDim.x * 4;
    for (int i = gw; i < N_NODES; i += nw) {
        int beg = __builtin_amdgcn_readfirstlane(rowp[i]);
        int end = __builtin_amdgcn_readfirstlane(rowp[i + 1]);
        float a0 = 0.f, a1 = 0.f;
        gather_rows(h2, col, beg, end, lane, c, a0, a1);
        a0 += __shfl_xor(a0, 32, 64);
        a1 += __shfl_xor(a1, 32, 64);
        if (lane < 32) {
            float2 hv = ((const float2*)(hin32 + i * FDIM))[c];
            float degf = (float)(end - beg + 1);
            sm4[wid][c] = make_float4(degf * hv.x, a0 + hv.x,
                                      degf * hv.y, a1 + hv.y);
        }
        float acc = base[i * FDIM + lane];
        const float4* s4 = (const float4*)sm4[wid];
#pragma unroll
        for (int m2 = 0; m2 < 32; m2++) {
            float4 v = s4[m2];
            acc = fmaf(v.x, w1[2 * m2], acc);
            acc = fmaf(v.y, w2[2 * m2], acc);
            acc = fmaf(v.z, w1[2 * m2 + 1], acc);
            acc = fmaf(v.w, w2[2 * m2 + 1], acc);
        }
        float h = fmaxf(acc, 0.f);
        hout32[i * FDIM + lane] = h;
        hout16[i * FDIM + lane] = __float2half(h);
    }
}

// out = relu( (deg*h)@Wom1 + (A h)@Wom2 + obase ); scalar = out.Wout; atomic pool
__global__ void k_out(const float* __restrict__ hin32, const __half* __restrict__ hin16,
                      const float* __restrict__ obase,
                      const int* __restrict__ rowp, const int* __restrict__ col,
                      const float* __restrict__ Wom,
                      const float* __restrict__ Wout,
                      const int* __restrict__ batch,
                      float* __restrict__ dout) {
    __shared__ __align__(16) float4 sm4[4][FDIM / 2];
    int lane = threadIdx.x & 63, wid = threadIdx.x >> 6;
    int c = lane & 31;
    float w1[FDIM], w2[FDIM];
#pragma unroll
    for (int m = 0; m < FDIM; m++) {
        w1[m] = Wom[m * FDIM + lane];
        w2[m] = Wom[(FDIM + m) * FDIM + lane];
    }
    float wo = Wout[lane];
    const __half2* h2 = (const __half2*)hin16;
    int gw = blockIdx.x * 4 + wid, nw = gridDim.x * 4;
    for (int i = gw; i < N_NODES; i += nw) {
        int beg = __builtin_amdgcn_readfirstlane(rowp[i]);
        int end = __builtin_amdgcn_readfirstlane(rowp[i + 1]);
        float a0 = 0.f, a1 = 0.f;
        gather_rows(h2, col, beg, end, lane, c, a0, a1);
        a0 += __shfl_xor(a0, 32, 64);
        a1 += __shfl_xor(a1, 32, 64);
        if (lane < 32) {
            float2 hv = ((const float2*)(hin32 + i * FDIM))[c];
            float degf = (float)(end - beg + 1);
            sm4[wid][c] = make_float4(degf * hv.x, a0 + hv.x,
                                      degf * hv.y, a1 + hv.y);
        }
        float acc = obase[i * FDIM + lane];
        const float4* s4 = (const float4*)sm4[wid];
#pragma unroll
        for (int m2 = 0; m2 < 32; m2++) {
            float4 v = s4[m2];
            acc = fmaf(v.x, w1[2 * m2], acc);
            acc = fmaf(v.y, w2[2 * m2], acc);
            acc = fmaf(v.z, w1[2 * m2 + 1], acc);
            acc = fmaf(v.w, w2[2 * m2 + 1], acc);
        }
        float outk = fmaxf(acc, 0.f);
        float cc = outk * wo;
#pragma unroll
        for (int off = 32; off > 0; off >>= 1) cc += __shfl_down(cc, off, 64);
        if (lane == 0) atomicAdd(&dout[batch[i]], cc);
    }
}

// ---------------- launcher ----------------

extern "C" void kernel_launch(void* const* d_in, const int* in_sizes, int n_in,
                              void* d_out, int out_size, void* d_ws, size_t ws_size,
                              hipStream_t stream) {
    const float* x         = (const float*)d_in[0];
    const float* edge_attr = (const float*)d_in[1];
    const float* Wnh       = (const float*)d_in[2];
    const float* bnh       = (const float*)d_in[3];
    const float* Wmh       = (const float*)d_in[4];
    const float* bmh       = (const float*)d_in[5];
    const float* Wom       = (const float*)d_in[6];
    const float* bom       = (const float*)d_in[7];
    const float* Wout      = (const float*)d_in[8];
    const float* bout      = (const float*)d_in[9];
    const int*   eidx      = (const int*)d_in[10];
    const int*   batch     = (const int*)d_in[11];
    const int*   srcI = eidx;             // edge_index[0] : source (x_j)
    const int*   dstI = eidx + N_EDGES;   // edge_index[1] : target (aggregation)
    float* out = (float*)d_out;
    (void)in_sizes; (void)n_in; (void)out_size;

    char* w = (char*)d_ws;
    size_t off = 0;
    auto take = [&](size_t b) -> void* {
        void* p = w + off;
        off = (off + b + 255) & ~(size_t)255;
        return p;
    };
    float*  ea    = (float*)take((size_t)N_NODES * EDIM * 4);
    int*    cnt   = (int*)take((size_t)N_NODES * 4);
    int*    rowp  = (int*)take((size_t)(N_NODES + 1) * 4);
    int*    cur   = (int*)take((size_t)N_NODES * 4);
    int*    col   = (int*)take((size_t)N_EDGES * 4);
    float*  base  = (float*)take((size_t)N_NODES * FDIM * 4);
    float*  obase = (float*)take((size_t)N_NODES * FDIM * 4);
    float*  hA    = (float*)take((size_t)N_NODES * FDIM * 4);
    float*  hB    = (float*)take((size_t)N_NODES * FDIM * 4);
    __half* x16   = (__half*)take((size_t)N_NODES * FDIM * 2);
    __half* hA16  = (__half*)take((size_t)N_NODES * FDIM * 2);
    __half* hB16  = (__half*)take((size_t)N_NODES * FDIM * 2);
    (void)ws_size;

    hipMemsetAsync(cnt, 0, (size_t)N_NODES * 4, stream);
    hipMemsetAsync(ea, 0, (size_t)N_NODES * EDIM * 4, stream);
    k_init_out<<<1, 256, 0, stream>>>(out, bout);
    k_count<<<(N_EDGES + 255) / 256, 256, 0, stream>>>(dstI, cnt);
    k_ea_scatter<<<(N_EDGES * EDIM + 255) / 256, 256, 0, stream>>>(dstI, edge_attr, ea);
    k_cvt_x<<<(N_NODES * FDIM + 255) / 256, 256, 0, stream>>>(x, x16);
    k_scan<<<1, 1024, 0, stream>>>(cnt, rowp, cur);
    k_fill<<<(N_EDGES + 255) / 256, 256, 0, stream>>>(srcI, dstI, cur, col);
    k_h0base<<<2048, 256, 0, stream>>>(x, ea, Wnh, bnh, Wmh, bmh, hA, hA16, base);
    k_obase<<<2048, 256, 0, stream>>>(x, x16, rowp, col, Wom, bom, obase);
    k_layer<<<2048, 256, 0, stream>>>(hA, hA16, base, rowp, col, Wmh, hB, hB16);
    k_layer<<<2048, 256, 0, stream>>>(hB, hB16, base, rowp, col, Wmh, hA, hA16);
    k_layer<<<2048, 256, 0, stream>>>(hA, hA16, base, rowp, col, Wmh, hB, hB16);
    k_out<<<2048, 256, 0, stream>>>(hB, hB16, obase, rowp, col, Wom, Wout, batch, out);
}